// Round 11
// baseline (529.661 us; speedup 1.0000x reference)
//
#include <hip/hip_runtime.h>

#define PP 8192
#define DD 512
#define NJT (PP / 64)

typedef short bf16x8 __attribute__((ext_vector_type(8)));
typedef float f32x4 __attribute__((ext_vector_type(4)));
typedef unsigned short u16;
typedef unsigned int u32;

__device__ __forceinline__ u16 f2bf(float x) {
  u32 u = __float_as_uint(x);
  u += 0x7fffu + ((u >> 16) & 1u);   // RNE
  return (u16)(u >> 16);
}
__device__ __forceinline__ float bf2f(u16 h) {
  return __uint_as_float(((u32)h) << 16);
}
__device__ __forceinline__ f32x4 mfma_bf16(bf16x8 a, bf16x8 b, f32x4 c) {
  return __builtin_amdgcn_mfma_f32_16x16x32_bf16(a, b, c, 0, 0, 0);
}
__device__ __forceinline__ void gload_lds16(const u16* g, u16* l) {
  __builtin_amdgcn_global_load_lds(
      (const __attribute__((address_space(1))) void*)g,
      (__attribute__((address_space(3))) void*)l, 16, 0, 0);
}

// ---- prep: transpose Wq,Wk to bf16; Wv to bf16 ------------------------------
__global__ void prep_wt_kernel(const float* __restrict__ Wq, const float* __restrict__ Wk,
                               const float* __restrict__ Wv, u16* __restrict__ WqT,
                               u16* __restrict__ WkT, u16* __restrict__ Wvb) {
  int i = blockIdx.x * 256 + threadIdx.x;
  int a = i >> 9, k = i & 511;
  WqT[(size_t)k * DD + a] = f2bf(Wq[i]);
  WkT[(size_t)k * DD + a] = f2bf(Wk[i]);
  Wvb[i] = f2bf(Wv[i]);
}

// ---- kb[k] = (bq . Wk[:,k]) / sqrt(d) ---------------------------------------
__global__ void kb_kernel(const float* __restrict__ Wk, const float* __restrict__ bq,
                          float* __restrict__ kb) {
  int k = threadIdx.x;
  float s = 0.f;
  for (int a = 0; a < DD; ++a) s += bq[a] * Wk[(size_t)a * DD + k];
  kb[k] = s * 0.04419417382415922f;
}

// ---- prep F: bf16 + per-row (sq-norm, v-bias) from ROUNDED values -----------
__global__ void prep_f_kernel(const float* __restrict__ F, const float* __restrict__ kb,
                              u16* __restrict__ Fb, float2* __restrict__ nv) {
  int wid = threadIdx.x >> 6, lane = threadIdx.x & 63;
  int row = blockIdx.x * 4 + wid;
  const float* src = F + (size_t)row * DD + lane * 8;
  float4 a = *(const float4*)src;
  float4 b = *(const float4*)(src + 4);
  float v[8] = {a.x, a.y, a.z, a.w, b.x, b.y, b.z, b.w};
  const float* kp = kb + lane * 8;
  float4 ka = *(const float4*)kp;
  float4 kc = *(const float4*)(kp + 4);
  float kw[8] = {ka.x, ka.y, ka.z, ka.w, kc.x, kc.y, kc.z, kc.w};
  u16 h[8];
  float s = 0.f, d = 0.f;
#pragma unroll
  for (int j = 0; j < 8; ++j) {
    h[j] = f2bf(v[j]);
    float f = bf2f(h[j]);
    s += f * f;
    d += f * kw[j];
  }
  u32 pk[4];
#pragma unroll
  for (int j = 0; j < 4; ++j) pk[j] = (u32)h[2 * j] | ((u32)h[2 * j + 1] << 16);
  *(uint4*)(Fb + (size_t)row * DD + lane * 8) = make_uint4(pk[0], pk[1], pk[2], pk[3]);
#pragma unroll
  for (int dd = 1; dd < 64; dd <<= 1) { s += __shfl_xor(s, dd); d += __shfl_xor(d, dd); }
  if (lane == 0) nv[row] = make_float2(s, d);
}

// ---- MT = (Wq^T Wk)^T / sqrt(d) ---------------------------------------------
__global__ __launch_bounds__(256) void mt_kernel(const u16* __restrict__ WkT,
                                                 const u16* __restrict__ WqT,
                                                 u16* __restrict__ MT) {
  int lane = threadIdx.x & 63, wm = threadIdx.x >> 6;
  int l15 = lane & 15, lg = lane >> 4;
  int rowA = blockIdx.x * 64 + wm * 16 + l15;
  int rowC0 = blockIdx.x * 64 + wm * 16 + lg * 4;
  int colbase = blockIdx.y * 64;
  f32x4 z = {0.f, 0.f, 0.f, 0.f};
  f32x4 acc[4] = {z, z, z, z};
#pragma unroll
  for (int kk = 0; kk < 16; ++kk) {
    bf16x8 aF = *(const bf16x8*)(WkT + (size_t)rowA * DD + kk * 32 + lg * 8);
#pragma unroll
    for (int nf = 0; nf < 4; ++nf) {
      bf16x8 bW = *(const bf16x8*)(WqT + (size_t)(colbase + nf * 16 + l15) * DD + kk * 32 + lg * 8);
      acc[nf] = mfma_bf16(aF, bW, acc[nf]);
    }
  }
  const float isd = 0.04419417382415922f;
#pragma unroll
  for (int nf = 0; nf < 4; ++nf) {
    int col = colbase + nf * 16 + l15;
#pragma unroll
    for (int r = 0; r < 4; ++r)
      MT[(size_t)(rowC0 + r) * DD + col] = f2bf(acc[nf][r] * isd);
  }
}

// ---- G = Fb @ MT^T (mat 0) ; V = Fb @ Wv^T + bv -> Vt (mat 1) ---------------
__global__ __launch_bounds__(256) void gv_kernel(
    const u16* __restrict__ Fb, const u16* __restrict__ MT, const u16* __restrict__ Wvb,
    const float* __restrict__ bv, u16* __restrict__ G, u16* __restrict__ Vt) {
  int mat = blockIdx.z;
  const u16* W = (mat == 0) ? MT : Wvb;
  int lane = threadIdx.x & 63, wm = threadIdx.x >> 6;
  int l15 = lane & 15, lg = lane >> 4;
  int rowA = blockIdx.x * 64 + wm * 16 + l15;
  int rowC0 = blockIdx.x * 64 + wm * 16 + lg * 4;
  int colbase = blockIdx.y * 64;
  f32x4 z = {0.f, 0.f, 0.f, 0.f};
  f32x4 acc[4] = {z, z, z, z};
#pragma unroll
  for (int kk = 0; kk < 16; ++kk) {
    bf16x8 aF = *(const bf16x8*)(Fb + (size_t)rowA * DD + kk * 32 + lg * 8);
#pragma unroll
    for (int nf = 0; nf < 4; ++nf) {
      bf16x8 bW = *(const bf16x8*)(W + (size_t)(colbase + nf * 16 + l15) * DD + kk * 32 + lg * 8);
      acc[nf] = mfma_bf16(aF, bW, acc[nf]);
    }
  }
#pragma unroll
  for (int nf = 0; nf < 4; ++nf) {
    int col = colbase + nf * 16 + l15;
    if (mat == 1) {
      float bb = bv[col];
      ushort4 vv = make_ushort4(f2bf(acc[nf][0] + bb), f2bf(acc[nf][1] + bb),
                                f2bf(acc[nf][2] + bb), f2bf(acc[nf][3] + bb));
      *(ushort4*)(Vt + (size_t)col * PP + rowC0) = vv;
    } else {
#pragma unroll
      for (int r = 0; r < 4; ++r)
        G[(size_t)(rowC0 + r) * DD + col] = f2bf(acc[nf][r]);
    }
  }
}

// ---- Pass A v5: key-split grid (256,2) -> 2 blocks/CU -----------------------
// Round-10 autopsy: resources allowed 2 blocks/CU but grid was 256 on 256 CUs
// -- no second block existed. blockIdx.y in {0,1} owns half the key range
// (64 of 128 key-tiles). Per-block codegen/VGPR/LDS identical (116/64KB);
// Dist/P stores disjoint; Fb staging traffic unchanged (each block stages only
// its half); gf/ff loads duplicate x2 (256KB - noise). Partials: 8 slots.
__global__ __launch_bounds__(512)
__attribute__((amdgpu_waves_per_eu(2, 4))) void sd2_kernel(
    const u16* __restrict__ G, const u16* __restrict__ Fb,
    const float2* __restrict__ nv, const float* __restrict__ lamp,
    float* __restrict__ Dist, u16* __restrict__ P, float* __restrict__ partial) {
  const float lam = lamp[0];
  int lane = threadIdx.x & 63, wid = threadIdx.x >> 6;
  int wm = wid >> 2, wn = wid & 3;
  int l15 = lane & 15, lg = lane >> 4;
  int rowA = blockIdx.x * 32 + wm * 16 + l15;
  int rowC0 = blockIdx.x * 32 + wm * 16 + lg * 4;
  int kbase = blockIdx.y * (PP / 2);   // this block's key range

  __shared__ u16 Ftile[64][DD];   // 64 KiB SINGLE-buffered key tile

  bf16x8 gf[16], ff[16];
#pragma unroll
  for (int c = 0; c < 16; ++c) {
    gf[c] = *(const bf16x8*)(G + (size_t)rowA * DD + c * 32 + lg * 8);
    ff[c] = *(const bf16x8*)(Fb + (size_t)rowA * DD + c * 32 + lg * 8);
  }
  float ni[4];
#pragma unroll
  for (int r = 0; r < 4; ++r) ni[r] = nv[rowC0 + r].x;
  float rs[4] = {0.f, 0.f, 0.f, 0.f};
  f32x4 z = {0.f, 0.f, 0.f, 0.f};

  int kl = wn * 16 + l15;
  int swz = kl & 7;

#pragma unroll
  for (int t = 0; t < 8; ++t) {
    int row = wid * 8 + t;
    gload_lds16(Fb + (size_t)(kbase + row) * DD + ((lane ^ (row & 7)) * 8), &Ftile[row][0]);
  }
  __syncthreads();

#pragma unroll 1
  for (int jt = 0; jt < NJT / 2; ++jt) {
    int key0 = kbase + jt * 64;
    // S: qk = G.F^T and gram = F.F^T, 2 independent chains each
    const u16* ft = &Ftile[0][0];
    f32x4 sqk0 = z, sqk1 = z, sff0 = z, sff1 = z;
#pragma unroll
    for (int kk = 0; kk < 16; kk += 2) {
      bf16x8 bF0 = *(const bf16x8*)(ft + (size_t)kl * DD + (((kk * 4 + lg) ^ swz) * 8));
      bf16x8 bF1 = *(const bf16x8*)(ft + (size_t)kl * DD + ((((kk + 1) * 4 + lg) ^ swz) * 8));
      sqk0 = mfma_bf16(gf[kk], bF0, sqk0);
      sff0 = mfma_bf16(ff[kk], bF0, sff0);
      sqk1 = mfma_bf16(gf[kk + 1], bF1, sqk1);
      sff1 = mfma_bf16(ff[kk + 1], bF1, sff1);
    }
    __syncthreads();   // sync1: all S-reads of Ftile complete
    // stage next tile into the (now free) single buffer
    if (jt + 1 < NJT / 2) {
      int nk = key0 + 64;
#pragma unroll
      for (int t = 0; t < 8; ++t) {
        int row = wid * 8 + t;
        gload_lds16(Fb + (size_t)(nk + row) * DD + ((lane ^ (row & 7)) * 8), &Ftile[row][0]);
      }
    }
    // epilogue overlaps the staging loads (drained at sync2)
    int colB = key0 + kl;
    float2 nvj = nv[colB];
#pragma unroll
    for (int r = 0; r < 4; ++r) {
      float sq = ni[r] + nvj.x - 2.0f * (sff0[r] + sff1[r]);
      sq = fmaxf(sq, 0.f);
      float dist = sqrtf(sq);
      Dist[(size_t)(rowC0 + r) * PP + colB] = dist;
      float s = (sqk0[r] + sqk1[r]) + nvj.y - lam * dist;
      float p = __expf(fminf(s, 60.f));
      P[(size_t)(rowC0 + r) * PP + colB] = f2bf(p);
      rs[r] += p;
    }
    __syncthreads();   // sync2: staging drained; Ftile ready for next S
  }
#pragma unroll
  for (int d = 1; d < 16; d <<= 1) {
#pragma unroll
    for (int r = 0; r < 4; ++r) rs[r] += __shfl_xor(rs[r], d);
  }
  if (l15 == 0) {
#pragma unroll
    for (int r = 0; r < 4; ++r)
      partial[(size_t)(blockIdx.y * 4 + wn) * PP + rowC0 + r] = rs[r];
  }
}

// ---- rowsum[r] = sum over the 8 (key-split x wn) partials -------------------
__global__ void rowsum_kernel(const float* __restrict__ partial, float* __restrict__ rowsum) {
  int r = blockIdx.x * 256 + threadIdx.x;
  float s = 0.f;
#pragma unroll
  for (int cb = 0; cb < 8; ++cb) s += partial[(size_t)cb * PP + r];
  rowsum[r] = s;
}

// ---- Pass C v3: O = (P @ V) / rowsum (proven, UNCHANGED) --------------------
// grid (128, 4) = 512 blocks x 256 thr (4 waves) -> 2 independent blocks/CU.
#define KB 256
__global__ __launch_bounds__(256) void pv2_kernel(
    const u16* __restrict__ P, const u16* __restrict__ Vt,
    const float* __restrict__ rowsum, float* __restrict__ Fout) {
  int lane = threadIdx.x & 63, wid = threadIdx.x >> 6;
  int l15 = lane & 15, lg = lane >> 4;
  int q0 = blockIdx.x * 64;
  int col0 = blockIdx.y * 128 + wid * 32;
  __shared__ u16 Pt[2][64][KB];   // 2 x 32 KiB
  f32x4 z = {0.f, 0.f, 0.f, 0.f};
  f32x4 o[4][2] = {{z, z}, {z, z}, {z, z}, {z, z}};

#pragma unroll
  for (int i = 0; i < 8; ++i) {
    int row = wid * 16 + i * 2 + (lane >> 5);
    int g = (lane & 24) | ((lane & 7) ^ (row & 7));
    gload_lds16(P + (size_t)(q0 + row) * PP + g * 8, &Pt[0][wid * 16 + i * 2][0]);
  }
  __syncthreads();

#pragma unroll 1
  for (int kt = 0; kt < PP / KB; ++kt) {
    int cur = kt & 1;
    if (kt + 1 < PP / KB) {
      int k0n = (kt + 1) * KB;
#pragma unroll
      for (int i = 0; i < 8; ++i) {
        int row = wid * 16 + i * 2 + (lane >> 5);
        int g = (lane & 24) | ((lane & 7) ^ (row & 7));
        gload_lds16(P + (size_t)(q0 + row) * PP + k0n + g * 8,
                    &Pt[cur ^ 1][wid * 16 + i * 2][0]);
      }
    }
    int k0 = kt * KB;
#pragma unroll
    for (int kc = 0; kc < KB / 32; ++kc) {
      bf16x8 aP[4];
#pragma unroll
      for (int qf = 0; qf < 4; ++qf) {
        int row = qf * 16 + l15;
        int cg = kc * 4 + lg;
        int gp = (cg & 24) | ((cg & 7) ^ (row & 7));
        aP[qf] = *(const bf16x8*)(&Pt[cur][row][0] + gp * 8);
      }
#pragma unroll
      for (int nt = 0; nt < 2; ++nt) {
        int n = col0 + nt * 16 + l15;
        bf16x8 bV = *(const bf16x8*)(Vt + (size_t)n * PP + k0 + kc * 32 + lg * 8);
#pragma unroll
        for (int qf = 0; qf < 4; ++qf) o[qf][nt] = mfma_bf16(aP[qf], bV, o[qf][nt]);
      }
    }
    __syncthreads();
  }
  float inv[4][4];
#pragma unroll
  for (int qf = 0; qf < 4; ++qf)
#pragma unroll
    for (int r = 0; r < 4; ++r)
      inv[qf][r] = 1.0f / rowsum[q0 + qf * 16 + lg * 4 + r];
#pragma unroll
  for (int qf = 0; qf < 4; ++qf) {
#pragma unroll
    for (int nt = 0; nt < 2; ++nt) {
#pragma unroll
      for (int r = 0; r < 4; ++r)
        Fout[(size_t)(q0 + qf * 16 + lg * 4 + r) * DD + col0 + nt * 16 + l15] =
            o[qf][nt][r] * inv[qf][r];
    }
  }
}

// ---- fallback: round-2 fused flash attention (proven 890us) -----------------
__global__ __launch_bounds__(512)
__attribute__((amdgpu_waves_per_eu(2, 2))) void fused_kernel(
    const u16* __restrict__ G, const u16* __restrict__ Fb, const u16* __restrict__ Vt,
    const float2* __restrict__ nv, const float* __restrict__ lamp,
    float* __restrict__ out) {
  float* Fout = out;
  float* Dist = out + (size_t)PP * DD;
  const float lam = lamp[0];
  int lane = threadIdx.x & 63, wid = threadIdx.x >> 6;
  int wm = wid >> 2, wn = wid & 3;
  int l15 = lane & 15, lg = lane >> 4;
  int rowA = blockIdx.x * 32 + wm * 16 + l15;
  int rowC0 = blockIdx.x * 32 + wm * 16 + lg * 4;

  __shared__ u16 Ftile[2][64][DD];
  __shared__ u16 P_lds[32][72];
  __shared__ float redmax[8][16];
  __shared__ float redsum[8][16];

  bf16x8 gf[16], ff[16];
#pragma unroll
  for (int c = 0; c < 16; ++c) {
    gf[c] = *(const bf16x8*)(G + (size_t)rowA * DD + c * 32 + lg * 8);
    ff[c] = *(const bf16x8*)(Fb + (size_t)rowA * DD + c * 32 + lg * 8);
  }
  float ni[4];
#pragma unroll
  for (int r = 0; r < 4; ++r) ni[r] = nv[rowC0 + r].x;
  float m_run[2][4], l_run[2][4];
#pragma unroll
  for (int g = 0; g < 2; ++g)
#pragma unroll
    for (int r = 0; r < 4; ++r) { m_run[g][r] = -1e30f; l_run[g][r] = 0.f; }
  f32x4 z = {0.f, 0.f, 0.f, 0.f};
  f32x4 o[8] = {z, z, z, z, z, z, z, z};

  int kl = wn * 16 + l15;
  int swz = kl & 7;
  int col0 = wid * 64;

#pragma unroll
  for (int t = 0; t < 8; ++t) {
    int row = wid * 8 + t;
    gload_lds16(Fb + (size_t)row * DD + ((lane ^ (row & 7)) * 8), &Ftile[0][row][0]);
  }
  __syncthreads();

#pragma unroll 1
  for (int jt = 0; jt < NJT; ++jt) {
    int key0 = jt * 64;
    int cur = jt & 1;
    if (jt + 1 < NJT) {
      int nb = cur ^ 1;
#pragma unroll
      for (int t = 0; t < 8; ++t) {
        int row = wid * 8 + t;
        gload_lds16(Fb + (size_t)(key0 + 64 + row) * DD + ((lane ^ (row & 7)) * 8),
                    &Ftile[nb][row][0]);
      }
    }
    const u16* ft = &Ftile[cur][0][0];
    f32x4 sqk = z, sff = z;
#pragma unroll
    for (int kk = 0; kk < 16; ++kk) {
      bf16x8 bF = *(const bf16x8*)(ft + (size_t)kl * DD + (((kk * 4 + lg) ^ swz) * 8));
      sqk = mfma_bf16(gf[kk], bF, sqk);
      sff = mfma_bf16(ff[kk], bF, sff);
    }
    int colB = key0 + kl;
    float2 nvj = nv[colB];
    float pv[4], tmax[4];
#pragma unroll
    for (int r = 0; r < 4; ++r) {
      float sq = ni[r] + nvj.x - 2.0f * sff[r];
      sq = fmaxf(sq, 0.f);
      float dist = sqrtf(sq);
      Dist[(size_t)(rowC0 + r) * PP + colB] = dist;
      float s = sqk[r] + nvj.y - lam * dist;
      pv[r] = s;
      tmax[r] = s;
    }
#pragma unroll
    for (int d = 1; d < 16; d <<= 1) {
#pragma unroll
      for (int r = 0; r < 4; ++r) tmax[r] = fmaxf(tmax[r], __shfl_xor(tmax[r], d));
    }
    if (l15 == 0) {
#pragma unroll
      for (int r = 0; r < 4; ++r) redmax[wid][lg * 4 + r] = tmax[r];
    }
    __syncthreads();
    float mnew[2][4], alpha[2][4];
#pragma unroll
    for (int g = 0; g < 2; ++g) {
#pragma unroll
      for (int r = 0; r < 4; ++r) {
        float mt = m_run[g][r];
#pragma unroll
        for (int ow = 0; ow < 4; ++ow) mt = fmaxf(mt, redmax[g * 4 + ow][lg * 4 + r]);
        mnew[g][r] = mt;
        alpha[g][r] = __expf(m_run[g][r] - mt);
      }
    }
    float tsum[4];
#pragma unroll
    for (int r = 0; r < 4; ++r) {
      float mo = (wm == 0) ? mnew[0][r] : mnew[1][r];
      pv[r] = __expf(pv[r] - mo);
      tsum[r] = pv[r];
    }
#pragma unroll
    for (int d = 1; d < 16; d <<= 1) {
#pragma unroll
      for (int r = 0; r < 4; ++r) tsum[r] += __shfl_xor(tsum[r], d);
    }
#pragma unroll
    for (int r = 0; r < 4; ++r)
      P_lds[wm * 16 + lg * 4 + r][wn * 16 + l15] = f2bf(pv[r]);
    if (l15 == 0) {
#pragma unroll
      for (int r = 0; r < 4; ++r) redsum[wid][lg * 4 + r] = tsum[r];
    }
    __syncthreads();
#pragma unroll
    for (int g = 0; g < 2; ++g) {
#pragma unroll
      for (int r = 0; r < 4; ++r) {
        float s4 = 0.f;
#pragma unroll
        for (int ow = 0; ow < 4; ++ow) s4 += redsum[g * 4 + ow][lg * 4 + r];
        l_run[g][r] = l_run[g][r] * alpha[g][r] + s4;
        m_run[g][r] = mnew[g][r];
      }
    }
#pragma unroll
    for (int g = 0; g < 2; ++g) {
#pragma unroll
      for (int nt = 0; nt < 4; ++nt) {
#pragma unroll
        for (int r = 0; r < 4; ++r) o[g * 4 + nt][r] *= alpha[g][r];
      }
    }
#pragma unroll
    for (int kc = 0; kc < 2; ++kc) {
      bf16x8 aP0 = *(const bf16x8*)(&P_lds[l15][kc * 32 + lg * 8]);
      bf16x8 aP1 = *(const bf16x8*)(&P_lds[16 + l15][kc * 32 + lg * 8]);
#pragma unroll
      for (int nt = 0; nt < 4; ++nt) {
        int n = col0 + nt * 16 + l15;
        bf16x8 bV = *(const bf16x8*)(Vt + (size_t)n * PP + key0 + kc * 32 + lg * 8);
        o[nt] = mfma_bf16(aP0, bV, o[nt]);
        o[4 + nt] = mfma_bf16(aP1, bV, o[4 + nt]);
      }
    }
  }
  float inv[2][4];
#pragma unroll
  for (int g = 0; g < 2; ++g)
#pragma unroll
    for (int r = 0; r < 4; ++r) inv[g][r] = 1.0f / l_run[g][r];
#pragma unroll
  for (int g = 0; g < 2; ++g) {
#pragma unroll
    for (int nt = 0; nt < 4; ++nt) {
#pragma unroll
      for (int r = 0; r < 4; ++r)
        Fout[(size_t)(blockIdx.x * 32 + g * 16 + lg * 4 + r) * DD + col0 + nt * 16 + l15] =
            o[g * 4 + nt][r] * inv[g][r];
    }
  }
}

extern "C" void kernel_launch(void* const* d_in, const int* in_sizes, int n_in,
                              void* d_out, int out_size, void* d_ws, size_t ws_size,
                              hipStream_t stream) {
  const float* F   = (const float*)d_in[0];
  const float* Wq  = (const float*)d_in[1];
  const float* bq  = (const float*)d_in[2];
  const float* Wk  = (const float*)d_in[3];
  const float* bk  = (const float*)d_in[4];
  const float* Wv  = (const float*)d_in[5];
  const float* bv  = (const float*)d_in[6];
  const float* lam = (const float*)d_in[7];
  float* out = (float*)d_out;
  (void)bk;

  u16* ws  = (u16*)d_ws;
  u16* Fb  = ws;                               // [PP][DD]
  u16* G   = Fb + (size_t)PP * DD;             // [PP][DD]
  u16* Vt  = G + (size_t)PP * DD;              // [DD][PP]
  u16* WqT = Vt + (size_t)PP * DD;             // [DD][DD]
  u16* WkT = WqT + (size_t)DD * DD;
  u16* Wvb = WkT + (size_t)DD * DD;
  u16* MT  = Wvb + (size_t)DD * DD;
  float2* nv = (float2*)(MT + (size_t)DD * DD);  // [PP]
  float* kb  = (float*)(nv + PP);                // [DD]
  // decomposed path extras:
  u16* P        = (u16*)(kb + DD);               // [PP][PP] bf16, 134 MB
  float* partial = (float*)(P + (size_t)PP * PP); // [8][PP]
  float* rowsum  = partial + (size_t)8 * PP;     // [PP]
  size_t need = (size_t)((char*)(rowsum + PP) - (char*)d_ws);

  prep_wt_kernel<<<1024, 256, 0, stream>>>(Wq, Wk, Wv, WqT, WkT, Wvb);
  kb_kernel<<<1, 512, 0, stream>>>(Wk, bq, kb);
  prep_f_kernel<<<PP / 4, 256, 0, stream>>>(F, kb, Fb, nv);
  mt_kernel<<<dim3(8, 8), 256, 0, stream>>>(WkT, WqT, MT);
  gv_kernel<<<dim3(PP / 64, DD / 64, 2), 256, 0, stream>>>(Fb, MT, Wvb, bv, G, Vt);

  if (ws_size >= need) {
    float* Dist = out + (size_t)PP * DD;
    sd2_kernel<<<dim3(PP / 32, 2), 512, 0, stream>>>(G, Fb, nv, lam, Dist, P, partial);
    rowsum_kernel<<<PP / 256, 256, 0, stream>>>(partial, rowsum);
    pv2_kernel<<<dim3(PP / 64, 4), 256, 0, stream>>>(P, Vt, rowsum, out);
  } else {
    fused_kernel<<<PP / 32, 512, 0, stream>>>(G, Fb, Vt, nv, lam, out);
  }
}

// Round 12
// 507.225 us; speedup vs baseline: 1.0442x; 1.0442x over previous
//
#include <hip/hip_runtime.h>

#define PP 8192
#define DD 512
#define NJT (PP / 64)
#define NSPLIT 2
#define NJT3 (PP / NSPLIT / 32)

typedef short bf16x8 __attribute__((ext_vector_type(8)));
typedef float f32x4 __attribute__((ext_vector_type(4)));
typedef unsigned short u16;
typedef unsigned int u32;

__device__ __forceinline__ u16 f2bf(float x) {
  u32 u = __float_as_uint(x);
  u += 0x7fffu + ((u >> 16) & 1u);   // RNE
  return (u16)(u >> 16);
}
__device__ __forceinline__ float bf2f(u16 h) {
  return __uint_as_float(((u32)h) << 16);
}
__device__ __forceinline__ f32x4 mfma_bf16(bf16x8 a, bf16x8 b, f32x4 c) {
  return __builtin_amdgcn_mfma_f32_16x16x32_bf16(a, b, c, 0, 0, 0);
}
__device__ __forceinline__ void gload_lds16(const u16* g, u16* l) {
  __builtin_amdgcn_global_load_lds(
      (const __attribute__((address_space(1))) void*)g,
      (__attribute__((address_space(3))) void*)l, 16, 0, 0);
}

// ---- prep: transpose Wq,Wk to bf16; Wv to bf16 ------------------------------
__global__ void prep_wt_kernel(const float* __restrict__ Wq, const float* __restrict__ Wk,
                               const float* __restrict__ Wv, u16* __restrict__ WqT,
                               u16* __restrict__ WkT, u16* __restrict__ Wvb) {
  int i = blockIdx.x * 256 + threadIdx.x;
  int a = i >> 9, k = i & 511;
  WqT[(size_t)k * DD + a] = f2bf(Wq[i]);
  WkT[(size_t)k * DD + a] = f2bf(Wk[i]);
  Wvb[i] = f2bf(Wv[i]);
}

// ---- kb[k] = (bq . Wk[:,k]) / sqrt(d) ---------------------------------------
__global__ void kb_kernel(const float* __restrict__ Wk, const float* __restrict__ bq,
                          float* __restrict__ kb) {
  int k = threadIdx.x;
  float s = 0.f;
  for (int a = 0; a < DD; ++a) s += bq[a] * Wk[(size_t)a * DD + k];
  kb[k] = s * 0.04419417382415922f;
}

// ---- prep F: bf16 + per-row (sq-norm, v-bias) from ROUNDED values -----------
__global__ void prep_f_kernel(const float* __restrict__ F, const float* __restrict__ kb,
                              u16* __restrict__ Fb, float2* __restrict__ nv) {
  int wid = threadIdx.x >> 6, lane = threadIdx.x & 63;
  int row = blockIdx.x * 4 + wid;
  const float* src = F + (size_t)row * DD + lane * 8;
  float4 a = *(const float4*)src;
  float4 b = *(const float4*)(src + 4);
  float v[8] = {a.x, a.y, a.z, a.w, b.x, b.y, b.z, b.w};
  const float* kp = kb + lane * 8;
  float4 ka = *(const float4*)kp;
  float4 kc = *(const float4*)(kp + 4);
  float kw[8] = {ka.x, ka.y, ka.z, ka.w, kc.x, kc.y, kc.z, kc.w};
  u16 h[8];
  float s = 0.f, d = 0.f;
#pragma unroll
  for (int j = 0; j < 8; ++j) {
    h[j] = f2bf(v[j]);
    float f = bf2f(h[j]);
    s += f * f;
    d += f * kw[j];
  }
  u32 pk[4];
#pragma unroll
  for (int j = 0; j < 4; ++j) pk[j] = (u32)h[2 * j] | ((u32)h[2 * j + 1] << 16);
  *(uint4*)(Fb + (size_t)row * DD + lane * 8) = make_uint4(pk[0], pk[1], pk[2], pk[3]);
#pragma unroll
  for (int dd = 1; dd < 64; dd <<= 1) { s += __shfl_xor(s, dd); d += __shfl_xor(d, dd); }
  if (lane == 0) nv[row] = make_float2(s, d);
}

// ---- MT = (Wq^T Wk)^T / sqrt(d) ---------------------------------------------
__global__ __launch_bounds__(256) void mt_kernel(const u16* __restrict__ WkT,
                                                 const u16* __restrict__ WqT,
                                                 u16* __restrict__ MT) {
  int lane = threadIdx.x & 63, wm = threadIdx.x >> 6;
  int l15 = lane & 15, lg = lane >> 4;
  int rowA = blockIdx.x * 64 + wm * 16 + l15;
  int rowC0 = blockIdx.x * 64 + wm * 16 + lg * 4;
  int colbase = blockIdx.y * 64;
  f32x4 z = {0.f, 0.f, 0.f, 0.f};
  f32x4 acc[4] = {z, z, z, z};
#pragma unroll
  for (int kk = 0; kk < 16; ++kk) {
    bf16x8 aF = *(const bf16x8*)(WkT + (size_t)rowA * DD + kk * 32 + lg * 8);
#pragma unroll
    for (int nf = 0; nf < 4; ++nf) {
      bf16x8 bW = *(const bf16x8*)(WqT + (size_t)(colbase + nf * 16 + l15) * DD + kk * 32 + lg * 8);
      acc[nf] = mfma_bf16(aF, bW, acc[nf]);
    }
  }
  const float isd = 0.04419417382415922f;
#pragma unroll
  for (int nf = 0; nf < 4; ++nf) {
    int col = colbase + nf * 16 + l15;
#pragma unroll
    for (int r = 0; r < 4; ++r)
      MT[(size_t)(rowC0 + r) * DD + col] = f2bf(acc[nf][r] * isd);
  }
}

// ---- G = Fb @ MT^T (mat 0) ; V = Fb @ Wv^T + bv -> Vt (mat 1) ---------------
__global__ __launch_bounds__(256) void gv_kernel(
    const u16* __restrict__ Fb, const u16* __restrict__ MT, const u16* __restrict__ Wvb,
    const float* __restrict__ bv, u16* __restrict__ G, u16* __restrict__ Vt) {
  int mat = blockIdx.z;
  const u16* W = (mat == 0) ? MT : Wvb;
  int lane = threadIdx.x & 63, wm = threadIdx.x >> 6;
  int l15 = lane & 15, lg = lane >> 4;
  int rowA = blockIdx.x * 64 + wm * 16 + l15;
  int rowC0 = blockIdx.x * 64 + wm * 16 + lg * 4;
  int colbase = blockIdx.y * 64;
  f32x4 z = {0.f, 0.f, 0.f, 0.f};
  f32x4 acc[4] = {z, z, z, z};
#pragma unroll
  for (int kk = 0; kk < 16; ++kk) {
    bf16x8 aF = *(const bf16x8*)(Fb + (size_t)rowA * DD + kk * 32 + lg * 8);
#pragma unroll
    for (int nf = 0; nf < 4; ++nf) {
      bf16x8 bW = *(const bf16x8*)(W + (size_t)(colbase + nf * 16 + l15) * DD + kk * 32 + lg * 8);
      acc[nf] = mfma_bf16(aF, bW, acc[nf]);
    }
  }
#pragma unroll
  for (int nf = 0; nf < 4; ++nf) {
    int col = colbase + nf * 16 + l15;
    if (mat == 1) {
      float bb = bv[col];
      ushort4 vv = make_ushort4(f2bf(acc[nf][0] + bb), f2bf(acc[nf][1] + bb),
                                f2bf(acc[nf][2] + bb), f2bf(acc[nf][3] + bb));
      *(ushort4*)(Vt + (size_t)col * PP + rowC0) = vv;
    } else {
#pragma unroll
      for (int r = 0; r < 4; ++r)
        G[(size_t)(rowC0 + r) * DD + col] = f2bf(acc[nf][r]);
    }
  }
}

// ---- Pass A v6 (sd3): 4-wave blocks -> 2 blocks/CU within the 2-wave/SIMD
// register class.
// Round-11 autopsy: unified VGPR+AGPR total (116 arch + ~16 acc) > 128 ->
// 2 waves/SIMD class -> 8 waves/CU hard cap: one 8-wave block could NEVER
// share a CU. Fix = pv2's proven move: 256-thr (4-wave) blocks, tile
// 32 rows x 32 keys (wm2 x wn2, per-wave rate unchanged), key-split y{0,1},
// grid (256,2)=512 -> TWO decoupled barrier domains per CU.
// Ftile [2][32][DD] = 64KB/block dbuf (2 blocks = 128 <= 160KB LDS) ->
// back to ONE barrier/iter. Staging traffic unchanged (block stages its half).
__global__ __launch_bounds__(256)
__attribute__((amdgpu_waves_per_eu(2, 4))) void sd3_kernel(
    const u16* __restrict__ G, const u16* __restrict__ Fb,
    const float2* __restrict__ nv, const float* __restrict__ lamp,
    float* __restrict__ Dist, u16* __restrict__ P, float* __restrict__ partial) {
  const float lam = lamp[0];
  int lane = threadIdx.x & 63, wid = threadIdx.x >> 6;   // wid 0..3
  int wm = wid >> 1, wn = wid & 1;
  int l15 = lane & 15, lg = lane >> 4;
  int rowA = blockIdx.x * 32 + wm * 16 + l15;
  int rowC0 = blockIdx.x * 32 + wm * 16 + lg * 4;
  int kbase = blockIdx.y * (PP / NSPLIT);   // this block's key half

  __shared__ u16 Ftile[2][32][DD];   // 2 x 32 KiB double-buffered key tile

  bf16x8 gf[16], ff[16];
#pragma unroll
  for (int c = 0; c < 16; ++c) {
    gf[c] = *(const bf16x8*)(G + (size_t)rowA * DD + c * 32 + lg * 8);
    ff[c] = *(const bf16x8*)(Fb + (size_t)rowA * DD + c * 32 + lg * 8);
  }
  float ni[4];
#pragma unroll
  for (int r = 0; r < 4; ++r) ni[r] = nv[rowC0 + r].x;
  float rs[4] = {0.f, 0.f, 0.f, 0.f};
  f32x4 z = {0.f, 0.f, 0.f, 0.f};

  int kl = wn * 16 + l15;   // 0..31: key_local
  int swz = kl & 7;

  // prologue: stage tile 0 (4 waves x 8 rows)
#pragma unroll
  for (int t = 0; t < 8; ++t) {
    int row = wid * 8 + t;
    gload_lds16(Fb + (size_t)(kbase + row) * DD + ((lane ^ (row & 7)) * 8),
                &Ftile[0][row][0]);
  }
  __syncthreads();

#pragma unroll 1
  for (int jt = 0; jt < NJT3; ++jt) {
    int key0 = kbase + jt * 32;
    int cur = jt & 1;
    // stage next tile into the other buffer (in flight across S + epilogue)
    if (jt + 1 < NJT3) {
#pragma unroll
      for (int t = 0; t < 8; ++t) {
        int row = wid * 8 + t;
        gload_lds16(Fb + (size_t)(key0 + 32 + row) * DD + ((lane ^ (row & 7)) * 8),
                    &Ftile[cur ^ 1][row][0]);
      }
    }
    // S: qk = G.F^T and gram = F.F^T, 2 independent chains each
    const u16* ft = &Ftile[cur][0][0];
    f32x4 sqk0 = z, sqk1 = z, sff0 = z, sff1 = z;
#pragma unroll
    for (int kk = 0; kk < 16; kk += 2) {
      bf16x8 bF0 = *(const bf16x8*)(ft + (size_t)kl * DD + (((kk * 4 + lg) ^ swz) * 8));
      bf16x8 bF1 = *(const bf16x8*)(ft + (size_t)kl * DD + ((((kk + 1) * 4 + lg) ^ swz) * 8));
      sqk0 = mfma_bf16(gf[kk], bF0, sqk0);
      sff0 = mfma_bf16(ff[kk], bF0, sff0);
      sqk1 = mfma_bf16(gf[kk + 1], bF1, sqk1);
      sff1 = mfma_bf16(ff[kk + 1], bF1, sff1);
    }
    // epilogue (overlaps the in-flight staging; drained at the barrier)
    int colB = key0 + kl;
    float2 nvj = nv[colB];
#pragma unroll
    for (int r = 0; r < 4; ++r) {
      float sq = ni[r] + nvj.x - 2.0f * (sff0[r] + sff1[r]);
      sq = fmaxf(sq, 0.f);
      float dist = sqrtf(sq);
      Dist[(size_t)(rowC0 + r) * PP + colB] = dist;
      float s = (sqk0[r] + sqk1[r]) + nvj.y - lam * dist;
      float p = __expf(fminf(s, 60.f));
      P[(size_t)(rowC0 + r) * PP + colB] = f2bf(p);
      rs[r] += p;
    }
    __syncthreads();   // ONE barrier/iter: staging drained; buffer flip safe
  }
#pragma unroll
  for (int d = 1; d < 16; d <<= 1) {
#pragma unroll
    for (int r = 0; r < 4; ++r) rs[r] += __shfl_xor(rs[r], d);
  }
  if (l15 == 0) {
#pragma unroll
    for (int r = 0; r < 4; ++r)
      partial[(size_t)(blockIdx.y * 2 + wn) * PP + rowC0 + r] = rs[r];
  }
}

// ---- rowsum[r] = sum over the 4 (key-split x wn) partials -------------------
__global__ void rowsum_kernel(const float* __restrict__ partial, float* __restrict__ rowsum) {
  int r = blockIdx.x * 256 + threadIdx.x;
  float s = 0.f;
#pragma unroll
  for (int cb = 0; cb < 4; ++cb) s += partial[(size_t)cb * PP + r];
  rowsum[r] = s;
}

// ---- Pass C v3: O = (P @ V) / rowsum (proven, UNCHANGED) --------------------
// grid (128, 4) = 512 blocks x 256 thr (4 waves) -> 2 independent blocks/CU.
#define KB 256
__global__ __launch_bounds__(256) void pv2_kernel(
    const u16* __restrict__ P, const u16* __restrict__ Vt,
    const float* __restrict__ rowsum, float* __restrict__ Fout) {
  int lane = threadIdx.x & 63, wid = threadIdx.x >> 6;
  int l15 = lane & 15, lg = lane >> 4;
  int q0 = blockIdx.x * 64;
  int col0 = blockIdx.y * 128 + wid * 32;
  __shared__ u16 Pt[2][64][KB];   // 2 x 32 KiB
  f32x4 z = {0.f, 0.f, 0.f, 0.f};
  f32x4 o[4][2] = {{z, z}, {z, z}, {z, z}, {z, z}};

#pragma unroll
  for (int i = 0; i < 8; ++i) {
    int row = wid * 16 + i * 2 + (lane >> 5);
    int g = (lane & 24) | ((lane & 7) ^ (row & 7));
    gload_lds16(P + (size_t)(q0 + row) * PP + g * 8, &Pt[0][wid * 16 + i * 2][0]);
  }
  __syncthreads();

#pragma unroll 1
  for (int kt = 0; kt < PP / KB; ++kt) {
    int cur = kt & 1;
    if (kt + 1 < PP / KB) {
      int k0n = (kt + 1) * KB;
#pragma unroll
      for (int i = 0; i < 8; ++i) {
        int row = wid * 16 + i * 2 + (lane >> 5);
        int g = (lane & 24) | ((lane & 7) ^ (row & 7));
        gload_lds16(P + (size_t)(q0 + row) * PP + k0n + g * 8,
                    &Pt[cur ^ 1][wid * 16 + i * 2][0]);
      }
    }
    int k0 = kt * KB;
#pragma unroll
    for (int kc = 0; kc < KB / 32; ++kc) {
      bf16x8 aP[4];
#pragma unroll
      for (int qf = 0; qf < 4; ++qf) {
        int row = qf * 16 + l15;
        int cg = kc * 4 + lg;
        int gp = (cg & 24) | ((cg & 7) ^ (row & 7));
        aP[qf] = *(const bf16x8*)(&Pt[cur][row][0] + gp * 8);
      }
#pragma unroll
      for (int nt = 0; nt < 2; ++nt) {
        int n = col0 + nt * 16 + l15;
        bf16x8 bV = *(const bf16x8*)(Vt + (size_t)n * PP + k0 + kc * 32 + lg * 8);
#pragma unroll
        for (int qf = 0; qf < 4; ++qf) o[qf][nt] = mfma_bf16(aP[qf], bV, o[qf][nt]);
      }
    }
    __syncthreads();
  }
  float inv[4][4];
#pragma unroll
  for (int qf = 0; qf < 4; ++qf)
#pragma unroll
    for (int r = 0; r < 4; ++r)
      inv[qf][r] = 1.0f / rowsum[q0 + qf * 16 + lg * 4 + r];
#pragma unroll
  for (int qf = 0; qf < 4; ++qf) {
#pragma unroll
    for (int nt = 0; nt < 2; ++nt) {
#pragma unroll
      for (int r = 0; r < 4; ++r)
        Fout[(size_t)(q0 + qf * 16 + lg * 4 + r) * DD + col0 + nt * 16 + l15] =
            o[qf][nt][r] * inv[qf][r];
    }
  }
}

// ---- fallback: round-2 fused flash attention (proven 890us) -----------------
__global__ __launch_bounds__(512)
__attribute__((amdgpu_waves_per_eu(2, 2))) void fused_kernel(
    const u16* __restrict__ G, const u16* __restrict__ Fb, const u16* __restrict__ Vt,
    const float2* __restrict__ nv, const float* __restrict__ lamp,
    float* __restrict__ out) {
  float* Fout = out;
  float* Dist = out + (size_t)PP * DD;
  const float lam = lamp[0];
  int lane = threadIdx.x & 63, wid = threadIdx.x >> 6;
  int wm = wid >> 2, wn = wid & 3;
  int l15 = lane & 15, lg = lane >> 4;
  int rowA = blockIdx.x * 32 + wm * 16 + l15;
  int rowC0 = blockIdx.x * 32 + wm * 16 + lg * 4;

  __shared__ u16 Ftile[2][64][DD];
  __shared__ u16 P_lds[32][72];
  __shared__ float redmax[8][16];
  __shared__ float redsum[8][16];

  bf16x8 gf[16], ff[16];
#pragma unroll
  for (int c = 0; c < 16; ++c) {
    gf[c] = *(const bf16x8*)(G + (size_t)rowA * DD + c * 32 + lg * 8);
    ff[c] = *(const bf16x8*)(Fb + (size_t)rowA * DD + c * 32 + lg * 8);
  }
  float ni[4];
#pragma unroll
  for (int r = 0; r < 4; ++r) ni[r] = nv[rowC0 + r].x;
  float m_run[2][4], l_run[2][4];
#pragma unroll
  for (int g = 0; g < 2; ++g)
#pragma unroll
    for (int r = 0; r < 4; ++r) { m_run[g][r] = -1e30f; l_run[g][r] = 0.f; }
  f32x4 z = {0.f, 0.f, 0.f, 0.f};
  f32x4 o[8] = {z, z, z, z, z, z, z, z};

  int kl = wn * 16 + l15;
  int swz = kl & 7;
  int col0 = wid * 64;

#pragma unroll
  for (int t = 0; t < 8; ++t) {
    int row = wid * 8 + t;
    gload_lds16(Fb + (size_t)row * DD + ((lane ^ (row & 7)) * 8), &Ftile[0][row][0]);
  }
  __syncthreads();

#pragma unroll 1
  for (int jt = 0; jt < NJT; ++jt) {
    int key0 = jt * 64;
    int cur = jt & 1;
    if (jt + 1 < NJT) {
      int nb = cur ^ 1;
#pragma unroll
      for (int t = 0; t < 8; ++t) {
        int row = wid * 8 + t;
        gload_lds16(Fb + (size_t)(key0 + 64 + row) * DD + ((lane ^ (row & 7)) * 8),
                    &Ftile[nb][row][0]);
      }
    }
    const u16* ft = &Ftile[cur][0][0];
    f32x4 sqk = z, sff = z;
#pragma unroll
    for (int kk = 0; kk < 16; ++kk) {
      bf16x8 bF = *(const bf16x8*)(ft + (size_t)kl * DD + (((kk * 4 + lg) ^ swz) * 8));
      sqk = mfma_bf16(gf[kk], bF, sqk);
      sff = mfma_bf16(ff[kk], bF, sff);
    }
    int colB = key0 + kl;
    float2 nvj = nv[colB];
    float pv[4], tmax[4];
#pragma unroll
    for (int r = 0; r < 4; ++r) {
      float sq = ni[r] + nvj.x - 2.0f * sff[r];
      sq = fmaxf(sq, 0.f);
      float dist = sqrtf(sq);
      Dist[(size_t)(rowC0 + r) * PP + colB] = dist;
      float s = sqk[r] + nvj.y - lam * dist;
      pv[r] = s;
      tmax[r] = s;
    }
#pragma unroll
    for (int d = 1; d < 16; d <<= 1) {
#pragma unroll
      for (int r = 0; r < 4; ++r) tmax[r] = fmaxf(tmax[r], __shfl_xor(tmax[r], d));
    }
    if (l15 == 0) {
#pragma unroll
      for (int r = 0; r < 4; ++r) redmax[wid][lg * 4 + r] = tmax[r];
    }
    __syncthreads();
    float mnew[2][4], alpha[2][4];
#pragma unroll
    for (int g = 0; g < 2; ++g) {
#pragma unroll
      for (int r = 0; r < 4; ++r) {
        float mt = m_run[g][r];
#pragma unroll
        for (int ow = 0; ow < 4; ++ow) mt = fmaxf(mt, redmax[g * 4 + ow][lg * 4 + r]);
        mnew[g][r] = mt;
        alpha[g][r] = __expf(m_run[g][r] - mt);
      }
    }
    float tsum[4];
#pragma unroll
    for (int r = 0; r < 4; ++r) {
      float mo = (wm == 0) ? mnew[0][r] : mnew[1][r];
      pv[r] = __expf(pv[r] - mo);
      tsum[r] = pv[r];
    }
#pragma unroll
    for (int d = 1; d < 16; d <<= 1) {
#pragma unroll
      for (int r = 0; r < 4; ++r) tsum[r] += __shfl_xor(tsum[r], d);
    }
#pragma unroll
    for (int r = 0; r < 4; ++r)
      P_lds[wm * 16 + lg * 4 + r][wn * 16 + l15] = f2bf(pv[r]);
    if (l15 == 0) {
#pragma unroll
      for (int r = 0; r < 4; ++r) redsum[wid][lg * 4 + r] = tsum[r];
    }
    __syncthreads();
#pragma unroll
    for (int g = 0; g < 2; ++g) {
#pragma unroll
      for (int r = 0; r < 4; ++r) {
        float s4 = 0.f;
#pragma unroll
        for (int ow = 0; ow < 4; ++ow) s4 += redsum[g * 4 + ow][lg * 4 + r];
        l_run[g][r] = l_run[g][r] * alpha[g][r] + s4;
        m_run[g][r] = mnew[g][r];
      }
    }
#pragma unroll
    for (int g = 0; g < 2; ++g) {
#pragma unroll
      for (int nt = 0; nt < 4; ++nt) {
#pragma unroll
        for (int r = 0; r < 4; ++r) o[g * 4 + nt][r] *= alpha[g][r];
      }
    }
#pragma unroll
    for (int kc = 0; kc < 2; ++kc) {
      bf16x8 aP0 = *(const bf16x8*)(&P_lds[l15][kc * 32 + lg * 8]);
      bf16x8 aP1 = *(const bf16x8*)(&P_lds[16 + l15][kc * 32 + lg * 8]);
#pragma unroll
      for (int nt = 0; nt < 4; ++nt) {
        int n = col0 + nt * 16 + l15;
        bf16x8 bV = *(const bf16x8*)(Vt + (size_t)n * PP + key0 + kc * 32 + lg * 8);
        o[nt] = mfma_bf16(aP0, bV, o[nt]);
        o[4 + nt] = mfma_bf16(aP1, bV, o[4 + nt]);
      }
    }
  }
  float inv[2][4];
#pragma unroll
  for (int g = 0; g < 2; ++g)
#pragma unroll
    for (int r = 0; r < 4; ++r) inv[g][r] = 1.0f / l_run[g][r];
#pragma unroll
  for (int g = 0; g < 2; ++g) {
#pragma unroll
    for (int nt = 0; nt < 4; ++nt) {
#pragma unroll
      for (int r = 0; r < 4; ++r)
        Fout[(size_t)(blockIdx.x * 32 + g * 16 + lg * 4 + r) * DD + col0 + nt * 16 + l15] =
            o[g * 4 + nt][r] * inv[g][r];
    }
  }
}

extern "C" void kernel_launch(void* const* d_in, const int* in_sizes, int n_in,
                              void* d_out, int out_size, void* d_ws, size_t ws_size,
                              hipStream_t stream) {
  const float* F   = (const float*)d_in[0];
  const float* Wq  = (const float*)d_in[1];
  const float* bq  = (const float*)d_in[2];
  const float* Wk  = (const float*)d_in[3];
  const float* bk  = (const float*)d_in[4];
  const float* Wv  = (const float*)d_in[5];
  const float* bv  = (const float*)d_in[6];
  const float* lam = (const float*)d_in[7];
  float* out = (float*)d_out;
  (void)bk;

  u16* ws  = (u16*)d_ws;
  u16* Fb  = ws;                               // [PP][DD]
  u16* G   = Fb + (size_t)PP * DD;             // [PP][DD]
  u16* Vt  = G + (size_t)PP * DD;              // [DD][PP]
  u16* WqT = Vt + (size_t)PP * DD;             // [DD][DD]
  u16* WkT = WqT + (size_t)DD * DD;
  u16* Wvb = WkT + (size_t)DD * DD;
  u16* MT  = Wvb + (size_t)DD * DD;
  float2* nv = (float2*)(MT + (size_t)DD * DD);  // [PP]
  float* kb  = (float*)(nv + PP);                // [DD]
  // decomposed path extras:
  u16* P        = (u16*)(kb + DD);               // [PP][PP] bf16, 134 MB
  float* partial = (float*)(P + (size_t)PP * PP); // [4][PP]
  float* rowsum  = partial + (size_t)4 * PP;     // [PP]
  size_t need = (size_t)((char*)(rowsum + PP) - (char*)d_ws);

  prep_wt_kernel<<<1024, 256, 0, stream>>>(Wq, Wk, Wv, WqT, WkT, Wvb);
  kb_kernel<<<1, 512, 0, stream>>>(Wk, bq, kb);
  prep_f_kernel<<<PP / 4, 256, 0, stream>>>(F, kb, Fb, nv);
  mt_kernel<<<dim3(8, 8), 256, 0, stream>>>(WkT, WqT, MT);
  gv_kernel<<<dim3(PP / 64, DD / 64, 2), 256, 0, stream>>>(Fb, MT, Wvb, bv, G, Vt);

  if (ws_size >= need) {
    float* Dist = out + (size_t)PP * DD;
    sd3_kernel<<<dim3(PP / 32, NSPLIT), 256, 0, stream>>>(G, Fb, nv, lam, Dist, P, partial);
    rowsum_kernel<<<PP / 256, 256, 0, stream>>>(partial, rowsum);
    pv2_kernel<<<dim3(PP / 64, 4), 256, 0, stream>>>(P, Vt, rowsum, out);
  } else {
    fused_kernel<<<PP / 32, 512, 0, stream>>>(G, Fb, Vt, nv, lam, out);
  }
}

// Round 13
// 472.044 us; speedup vs baseline: 1.1221x; 1.0745x over previous
//
#include <hip/hip_runtime.h>

#define PP 8192
#define DD 512
#define NJT (PP / 64)
#define NSPLIT 2
#define NJT3 (PP / NSPLIT / 32)

typedef short bf16x8 __attribute__((ext_vector_type(8)));
typedef float f32x4 __attribute__((ext_vector_type(4)));
typedef unsigned short u16;
typedef unsigned int u32;

__device__ __forceinline__ u16 f2bf(float x) {
  u32 u = __float_as_uint(x);
  u += 0x7fffu + ((u >> 16) & 1u);   // RNE
  return (u16)(u >> 16);
}
__device__ __forceinline__ float bf2f(u16 h) {
  return __uint_as_float(((u32)h) << 16);
}
__device__ __forceinline__ f32x4 mfma_bf16(bf16x8 a, bf16x8 b, f32x4 c) {
  return __builtin_amdgcn_mfma_f32_16x16x32_bf16(a, b, c, 0, 0, 0);
}
__device__ __forceinline__ void gload_lds16(const u16* g, u16* l) {
  __builtin_amdgcn_global_load_lds(
      (const __attribute__((address_space(1))) void*)g,
      (__attribute__((address_space(3))) void*)l, 16, 0, 0);
}

// ---- prep: transpose Wq,Wk to bf16; Wv to bf16 ------------------------------
__global__ void prep_wt_kernel(const float* __restrict__ Wq, const float* __restrict__ Wk,
                               const float* __restrict__ Wv, u16* __restrict__ WqT,
                               u16* __restrict__ WkT, u16* __restrict__ Wvb) {
  int i = blockIdx.x * 256 + threadIdx.x;
  int a = i >> 9, k = i & 511;
  WqT[(size_t)k * DD + a] = f2bf(Wq[i]);
  WkT[(size_t)k * DD + a] = f2bf(Wk[i]);
  Wvb[i] = f2bf(Wv[i]);
}

// ---- kb[k] = (bq . Wk[:,k]) / sqrt(d), parallel -----------------------------
// Round-12 autopsy: 1-block version streamed 1 MB through a single CU
// (~20+ us serial). 16 blocks x 256 thr: 32 k-cols/block x 8 a-groups,
// coalesced 128B reads, LDS reduce.
__global__ void kb_kernel(const float* __restrict__ Wk, const float* __restrict__ bq,
                          float* __restrict__ kb) {
  __shared__ float red[8][32];
  int kloc = threadIdx.x & 31, ag = threadIdx.x >> 5;
  int k = blockIdx.x * 32 + kloc;
  float s = 0.f;
  for (int a = ag * 64; a < ag * 64 + 64; ++a) s += bq[a] * Wk[(size_t)a * DD + k];
  red[ag][kloc] = s;
  __syncthreads();
  if (threadIdx.x < 32) {
    float t = 0.f;
#pragma unroll
    for (int g = 0; g < 8; ++g) t += red[g][threadIdx.x];
    kb[blockIdx.x * 32 + threadIdx.x] = t * 0.04419417382415922f;
  }
}

// ---- prep F: bf16 + per-row (sq-norm, v-bias) from ROUNDED values -----------
__global__ void prep_f_kernel(const float* __restrict__ F, const float* __restrict__ kb,
                              u16* __restrict__ Fb, float2* __restrict__ nv) {
  int wid = threadIdx.x >> 6, lane = threadIdx.x & 63;
  int row = blockIdx.x * 4 + wid;
  const float* src = F + (size_t)row * DD + lane * 8;
  float4 a = *(const float4*)src;
  float4 b = *(const float4*)(src + 4);
  float v[8] = {a.x, a.y, a.z, a.w, b.x, b.y, b.z, b.w};
  const float* kp = kb + lane * 8;
  float4 ka = *(const float4*)kp;
  float4 kc = *(const float4*)(kp + 4);
  float kw[8] = {ka.x, ka.y, ka.z, ka.w, kc.x, kc.y, kc.z, kc.w};
  u16 h[8];
  float s = 0.f, d = 0.f;
#pragma unroll
  for (int j = 0; j < 8; ++j) {
    h[j] = f2bf(v[j]);
    float f = bf2f(h[j]);
    s += f * f;
    d += f * kw[j];
  }
  u32 pk[4];
#pragma unroll
  for (int j = 0; j < 4; ++j) pk[j] = (u32)h[2 * j] | ((u32)h[2 * j + 1] << 16);
  *(uint4*)(Fb + (size_t)row * DD + lane * 8) = make_uint4(pk[0], pk[1], pk[2], pk[3]);
#pragma unroll
  for (int dd = 1; dd < 64; dd <<= 1) { s += __shfl_xor(s, dd); d += __shfl_xor(d, dd); }
  if (lane == 0) nv[row] = make_float2(s, d);
}

// ---- MT = (Wq^T Wk)^T / sqrt(d) ---------------------------------------------
__global__ __launch_bounds__(256) void mt_kernel(const u16* __restrict__ WkT,
                                                 const u16* __restrict__ WqT,
                                                 u16* __restrict__ MT) {
  int lane = threadIdx.x & 63, wm = threadIdx.x >> 6;
  int l15 = lane & 15, lg = lane >> 4;
  int rowA = blockIdx.x * 64 + wm * 16 + l15;
  int rowC0 = blockIdx.x * 64 + wm * 16 + lg * 4;
  int colbase = blockIdx.y * 64;
  f32x4 z = {0.f, 0.f, 0.f, 0.f};
  f32x4 acc[4] = {z, z, z, z};
#pragma unroll
  for (int kk = 0; kk < 16; ++kk) {
    bf16x8 aF = *(const bf16x8*)(WkT + (size_t)rowA * DD + kk * 32 + lg * 8);
#pragma unroll
    for (int nf = 0; nf < 4; ++nf) {
      bf16x8 bW = *(const bf16x8*)(WqT + (size_t)(colbase + nf * 16 + l15) * DD + kk * 32 + lg * 8);
      acc[nf] = mfma_bf16(aF, bW, acc[nf]);
    }
  }
  const float isd = 0.04419417382415922f;
#pragma unroll
  for (int nf = 0; nf < 4; ++nf) {
    int col = colbase + nf * 16 + l15;
#pragma unroll
    for (int r = 0; r < 4; ++r)
      MT[(size_t)(rowC0 + r) * DD + col] = f2bf(acc[nf][r] * isd);
  }
}

// ---- G = Fb @ MT^T (mat 0) ; V = Fb @ Wv^T + bv -> Vt (mat 1) ---------------
__global__ __launch_bounds__(256) void gv_kernel(
    const u16* __restrict__ Fb, const u16* __restrict__ MT, const u16* __restrict__ Wvb,
    const float* __restrict__ bv, u16* __restrict__ G, u16* __restrict__ Vt) {
  int mat = blockIdx.z;
  const u16* W = (mat == 0) ? MT : Wvb;
  int lane = threadIdx.x & 63, wm = threadIdx.x >> 6;
  int l15 = lane & 15, lg = lane >> 4;
  int rowA = blockIdx.x * 64 + wm * 16 + l15;
  int rowC0 = blockIdx.x * 64 + wm * 16 + lg * 4;
  int colbase = blockIdx.y * 64;
  f32x4 z = {0.f, 0.f, 0.f, 0.f};
  f32x4 acc[4] = {z, z, z, z};
#pragma unroll
  for (int kk = 0; kk < 16; ++kk) {
    bf16x8 aF = *(const bf16x8*)(Fb + (size_t)rowA * DD + kk * 32 + lg * 8);
#pragma unroll
    for (int nf = 0; nf < 4; ++nf) {
      bf16x8 bW = *(const bf16x8*)(W + (size_t)(colbase + nf * 16 + l15) * DD + kk * 32 + lg * 8);
      acc[nf] = mfma_bf16(aF, bW, acc[nf]);
    }
  }
#pragma unroll
  for (int nf = 0; nf < 4; ++nf) {
    int col = colbase + nf * 16 + l15;
    if (mat == 1) {
      float bb = bv[col];
      ushort4 vv = make_ushort4(f2bf(acc[nf][0] + bb), f2bf(acc[nf][1] + bb),
                                f2bf(acc[nf][2] + bb), f2bf(acc[nf][3] + bb));
      *(ushort4*)(Vt + (size_t)col * PP + rowC0) = vv;
    } else {
#pragma unroll
      for (int r = 0; r < 4; ++r)
        G[(size_t)(rowC0 + r) * DD + col] = f2bf(acc[nf][r]);
    }
  }
}

// ---- Pass A (sd3): proven 256us structure, sqrt micro-trim only -------------
__global__ __launch_bounds__(256)
__attribute__((amdgpu_waves_per_eu(2, 4))) void sd3_kernel(
    const u16* __restrict__ G, const u16* __restrict__ Fb,
    const float2* __restrict__ nv, const float* __restrict__ lamp,
    float* __restrict__ Dist, u16* __restrict__ P, float* __restrict__ partial) {
  const float lam = lamp[0];
  int lane = threadIdx.x & 63, wid = threadIdx.x >> 6;   // wid 0..3
  int wm = wid >> 1, wn = wid & 1;
  int l15 = lane & 15, lg = lane >> 4;
  int rowA = blockIdx.x * 32 + wm * 16 + l15;
  int rowC0 = blockIdx.x * 32 + wm * 16 + lg * 4;
  int kbase = blockIdx.y * (PP / NSPLIT);   // this block's key half

  __shared__ u16 Ftile[2][32][DD];   // 2 x 32 KiB double-buffered key tile

  bf16x8 gf[16], ff[16];
#pragma unroll
  for (int c = 0; c < 16; ++c) {
    gf[c] = *(const bf16x8*)(G + (size_t)rowA * DD + c * 32 + lg * 8);
    ff[c] = *(const bf16x8*)(Fb + (size_t)rowA * DD + c * 32 + lg * 8);
  }
  float ni[4];
#pragma unroll
  for (int r = 0; r < 4; ++r) ni[r] = nv[rowC0 + r].x;
  float rs[4] = {0.f, 0.f, 0.f, 0.f};
  f32x4 z = {0.f, 0.f, 0.f, 0.f};

  int kl = wn * 16 + l15;   // 0..31: key_local
  int swz = kl & 7;

  // prologue: stage tile 0 (4 waves x 8 rows)
#pragma unroll
  for (int t = 0; t < 8; ++t) {
    int row = wid * 8 + t;
    gload_lds16(Fb + (size_t)(kbase + row) * DD + ((lane ^ (row & 7)) * 8),
                &Ftile[0][row][0]);
  }
  __syncthreads();

#pragma unroll 1
  for (int jt = 0; jt < NJT3; ++jt) {
    int key0 = kbase + jt * 32;
    int cur = jt & 1;
    // stage next tile into the other buffer (in flight across S + epilogue)
    if (jt + 1 < NJT3) {
#pragma unroll
      for (int t = 0; t < 8; ++t) {
        int row = wid * 8 + t;
        gload_lds16(Fb + (size_t)(key0 + 32 + row) * DD + ((lane ^ (row & 7)) * 8),
                    &Ftile[cur ^ 1][row][0]);
      }
    }
    // S: qk = G.F^T and gram = F.F^T, 2 independent chains each
    const u16* ft = &Ftile[cur][0][0];
    f32x4 sqk0 = z, sqk1 = z, sff0 = z, sff1 = z;
#pragma unroll
    for (int kk = 0; kk < 16; kk += 2) {
      bf16x8 bF0 = *(const bf16x8*)(ft + (size_t)kl * DD + (((kk * 4 + lg) ^ swz) * 8));
      bf16x8 bF1 = *(const bf16x8*)(ft + (size_t)kl * DD + ((((kk + 1) * 4 + lg) ^ swz) * 8));
      sqk0 = mfma_bf16(gf[kk], bF0, sqk0);
      sff0 = mfma_bf16(ff[kk], bF0, sff0);
      sqk1 = mfma_bf16(gf[kk + 1], bF1, sqk1);
      sff1 = mfma_bf16(ff[kk + 1], bF1, sff1);
    }
    // epilogue (overlaps the in-flight staging; drained at the barrier)
    int colB = key0 + kl;
    float2 nvj = nv[colB];
#pragma unroll
    for (int r = 0; r < 4; ++r) {
      float sq = ni[r] + nvj.x - 2.0f * (sff0[r] + sff1[r]);
      sq = fmaxf(sq, 0.f);
      float dist = __builtin_amdgcn_sqrtf(sq);   // raw v_sqrt_f32 (~1ulp; tol 0.25)
      Dist[(size_t)(rowC0 + r) * PP + colB] = dist;
      float s = (sqk0[r] + sqk1[r]) + nvj.y - lam * dist;
      float p = __expf(fminf(s, 60.f));
      P[(size_t)(rowC0 + r) * PP + colB] = f2bf(p);
      rs[r] += p;
    }
    __syncthreads();   // ONE barrier/iter: staging drained; buffer flip safe
  }
#pragma unroll
  for (int d = 1; d < 16; d <<= 1) {
#pragma unroll
    for (int r = 0; r < 4; ++r) rs[r] += __shfl_xor(rs[r], d);
  }
  if (l15 == 0) {
#pragma unroll
    for (int r = 0; r < 4; ++r)
      partial[(size_t)(blockIdx.y * 2 + wn) * PP + rowC0 + r] = rs[r];
  }
}

// ---- rowsum[r] = sum over the 4 (key-split x wn) partials -------------------
__global__ void rowsum_kernel(const float* __restrict__ partial, float* __restrict__ rowsum) {
  int r = blockIdx.x * 256 + threadIdx.x;
  float s = 0.f;
#pragma unroll
  for (int cb = 0; cb < 4; ++cb) s += partial[(size_t)cb * PP + r];
  rowsum[r] = s;
}

// ---- Pass C v4: O = (P @ V) / rowsum, software-pipelined --------------------
// Round-12 analysis: pv2's throughput floor is ~3k cyc/iter but it ran at
// ~14k -- L2/L3 latency on bV feeding dependent MFMAs. Fix: explicit 1-deep
// register pipeline (preload aP[4]+bV[2] for kc+1 before kc's MFMAs), and
// issue P-tile staging AFTER the kc=0 loads so vmcnt's in-order drain doesn't
// chain staging latency into the first MFMA group.
#define KB 256
__global__ __launch_bounds__(256) void pv2_kernel(
    const u16* __restrict__ P, const u16* __restrict__ Vt,
    const float* __restrict__ rowsum, float* __restrict__ Fout) {
  int lane = threadIdx.x & 63, wid = threadIdx.x >> 6;
  int l15 = lane & 15, lg = lane >> 4;
  int q0 = blockIdx.x * 64;
  int col0 = blockIdx.y * 128 + wid * 32;
  __shared__ u16 Pt[2][64][KB];   // 2 x 32 KiB
  f32x4 z = {0.f, 0.f, 0.f, 0.f};
  f32x4 o[4][2] = {{z, z}, {z, z}, {z, z}, {z, z}};

#pragma unroll
  for (int i = 0; i < 8; ++i) {
    int row = wid * 16 + i * 2 + (lane >> 5);
    int g = (lane & 24) | ((lane & 7) ^ (row & 7));
    gload_lds16(P + (size_t)(q0 + row) * PP + g * 8, &Pt[0][wid * 16 + i * 2][0]);
  }
  __syncthreads();

#pragma unroll 1
  for (int kt = 0; kt < PP / KB; ++kt) {
    int cur = kt & 1;
    int k0 = kt * KB;
    // preload kc=0 operands FIRST (their vmcnt waits must not include staging)
    bf16x8 aPc[4], bVc[2];
#pragma unroll
    for (int qf = 0; qf < 4; ++qf) {
      int row = qf * 16 + l15;
      int gp = ((0 * 4 + lg) & 24) | (((0 * 4 + lg) & 7) ^ (row & 7));
      aPc[qf] = *(const bf16x8*)(&Pt[cur][row][0] + gp * 8);
    }
#pragma unroll
    for (int nt = 0; nt < 2; ++nt) {
      int n = col0 + nt * 16 + l15;
      bVc[nt] = *(const bf16x8*)(Vt + (size_t)n * PP + k0 + lg * 8);
    }
    // stage next P tile (drained at the end-of-iter barrier)
    if (kt + 1 < PP / KB) {
      int k0n = (kt + 1) * KB;
#pragma unroll
      for (int i = 0; i < 8; ++i) {
        int row = wid * 16 + i * 2 + (lane >> 5);
        int g = (lane & 24) | ((lane & 7) ^ (row & 7));
        gload_lds16(P + (size_t)(q0 + row) * PP + k0n + g * 8,
                    &Pt[cur ^ 1][wid * 16 + i * 2][0]);
      }
    }
#pragma unroll
    for (int kc = 0; kc < KB / 32; ++kc) {
      bf16x8 aPn[4], bVn[2];
      if (kc + 1 < KB / 32) {
        int cgn = (kc + 1) * 4 + lg;
#pragma unroll
        for (int qf = 0; qf < 4; ++qf) {
          int row = qf * 16 + l15;
          int gp = (cgn & 24) | ((cgn & 7) ^ (row & 7));
          aPn[qf] = *(const bf16x8*)(&Pt[cur][row][0] + gp * 8);
        }
#pragma unroll
        for (int nt = 0; nt < 2; ++nt) {
          int n = col0 + nt * 16 + l15;
          bVn[nt] = *(const bf16x8*)(Vt + (size_t)n * PP + k0 + (kc + 1) * 32 + lg * 8);
        }
      }
#pragma unroll
      for (int nt = 0; nt < 2; ++nt) {
#pragma unroll
        for (int qf = 0; qf < 4; ++qf) o[qf][nt] = mfma_bf16(aPc[qf], bVc[nt], o[qf][nt]);
      }
      if (kc + 1 < KB / 32) {
#pragma unroll
        for (int qf = 0; qf < 4; ++qf) aPc[qf] = aPn[qf];
        bVc[0] = bVn[0];
        bVc[1] = bVn[1];
      }
    }
    __syncthreads();
  }
  float inv[4][4];
#pragma unroll
  for (int qf = 0; qf < 4; ++qf)
#pragma unroll
    for (int r = 0; r < 4; ++r)
      inv[qf][r] = 1.0f / rowsum[q0 + qf * 16 + lg * 4 + r];
#pragma unroll
  for (int qf = 0; qf < 4; ++qf) {
#pragma unroll
    for (int nt = 0; nt < 2; ++nt) {
#pragma unroll
      for (int r = 0; r < 4; ++r)
        Fout[(size_t)(q0 + qf * 16 + lg * 4 + r) * DD + col0 + nt * 16 + l15] =
            o[qf][nt][r] * inv[qf][r];
    }
  }
}

// ---- fallback: round-2 fused flash attention (proven 890us) -----------------
__global__ __launch_bounds__(512)
__attribute__((amdgpu_waves_per_eu(2, 2))) void fused_kernel(
    const u16* __restrict__ G, const u16* __restrict__ Fb, const u16* __restrict__ Vt,
    const float2* __restrict__ nv, const float* __restrict__ lamp,
    float* __restrict__ out) {
  float* Fout = out;
  float* Dist = out + (size_t)PP * DD;
  const float lam = lamp[0];
  int lane = threadIdx.x & 63, wid = threadIdx.x >> 6;
  int wm = wid >> 2, wn = wid & 3;
  int l15 = lane & 15, lg = lane >> 4;
  int rowA = blockIdx.x * 32 + wm * 16 + l15;
  int rowC0 = blockIdx.x * 32 + wm * 16 + lg * 4;

  __shared__ u16 Ftile[2][64][DD];
  __shared__ u16 P_lds[32][72];
  __shared__ float redmax[8][16];
  __shared__ float redsum[8][16];

  bf16x8 gf[16], ff[16];
#pragma unroll
  for (int c = 0; c < 16; ++c) {
    gf[c] = *(const bf16x8*)(G + (size_t)rowA * DD + c * 32 + lg * 8);
    ff[c] = *(const bf16x8*)(Fb + (size_t)rowA * DD + c * 32 + lg * 8);
  }
  float ni[4];
#pragma unroll
  for (int r = 0; r < 4; ++r) ni[r] = nv[rowC0 + r].x;
  float m_run[2][4], l_run[2][4];
#pragma unroll
  for (int g = 0; g < 2; ++g)
#pragma unroll
    for (int r = 0; r < 4; ++r) { m_run[g][r] = -1e30f; l_run[g][r] = 0.f; }
  f32x4 z = {0.f, 0.f, 0.f, 0.f};
  f32x4 o[8] = {z, z, z, z, z, z, z, z};

  int kl = wn * 16 + l15;
  int swz = kl & 7;
  int col0 = wid * 64;

#pragma unroll
  for (int t = 0; t < 8; ++t) {
    int row = wid * 8 + t;
    gload_lds16(Fb + (size_t)row * DD + ((lane ^ (row & 7)) * 8), &Ftile[0][row][0]);
  }
  __syncthreads();

#pragma unroll 1
  for (int jt = 0; jt < NJT; ++jt) {
    int key0 = jt * 64;
    int cur = jt & 1;
    if (jt + 1 < NJT) {
      int nb = cur ^ 1;
#pragma unroll
      for (int t = 0; t < 8; ++t) {
        int row = wid * 8 + t;
        gload_lds16(Fb + (size_t)(key0 + 64 + row) * DD + ((lane ^ (row & 7)) * 8),
                    &Ftile[nb][row][0]);
      }
    }
    const u16* ft = &Ftile[cur][0][0];
    f32x4 sqk = z, sff = z;
#pragma unroll
    for (int kk = 0; kk < 16; ++kk) {
      bf16x8 bF = *(const bf16x8*)(ft + (size_t)kl * DD + (((kk * 4 + lg) ^ swz) * 8));
      sqk = mfma_bf16(gf[kk], bF, sqk);
      sff = mfma_bf16(ff[kk], bF, sff);
    }
    int colB = key0 + kl;
    float2 nvj = nv[colB];
    float pv[4], tmax[4];
#pragma unroll
    for (int r = 0; r < 4; ++r) {
      float sq = ni[r] + nvj.x - 2.0f * sff[r];
      sq = fmaxf(sq, 0.f);
      float dist = sqrtf(sq);
      Dist[(size_t)(rowC0 + r) * PP + colB] = dist;
      float s = sqk[r] + nvj.y - lam * dist;
      pv[r] = s;
      tmax[r] = s;
    }
#pragma unroll
    for (int d = 1; d < 16; d <<= 1) {
#pragma unroll
      for (int r = 0; r < 4; ++r) tmax[r] = fmaxf(tmax[r], __shfl_xor(tmax[r], d));
    }
    if (l15 == 0) {
#pragma unroll
      for (int r = 0; r < 4; ++r) redmax[wid][lg * 4 + r] = tmax[r];
    }
    __syncthreads();
    float mnew[2][4], alpha[2][4];
#pragma unroll
    for (int g = 0; g < 2; ++g) {
#pragma unroll
      for (int r = 0; r < 4; ++r) {
        float mt = m_run[g][r];
#pragma unroll
        for (int ow = 0; ow < 4; ++ow) mt = fmaxf(mt, redmax[g * 4 + ow][lg * 4 + r]);
        mnew[g][r] = mt;
        alpha[g][r] = __expf(m_run[g][r] - mt);
      }
    }
    float tsum[4];
#pragma unroll
    for (int r = 0; r < 4; ++r) {
      float mo = (wm == 0) ? mnew[0][r] : mnew[1][r];
      pv[r] = __expf(pv[r] - mo);
      tsum[r] = pv[r];
    }
#pragma unroll
    for (int d = 1; d < 16; d <<= 1) {
#pragma unroll
      for (int r = 0; r < 4; ++r) tsum[r] += __shfl_xor(tsum[r], d);
    }
#pragma unroll
    for (int r = 0; r < 4; ++r)
      P_lds[wm * 16 + lg * 4 + r][wn * 16 + l15] = f2bf(pv[r]);
    if (l15 == 0) {
#pragma unroll
      for (int r = 0; r < 4; ++r) redsum[wid][lg * 4 + r] = tsum[r];
    }
    __syncthreads();
#pragma unroll
    for (int g = 0; g < 2; ++g) {
#pragma unroll
      for (int r = 0; r < 4; ++r) {
        float s4 = 0.f;
#pragma unroll
        for (int ow = 0; ow < 4; ++ow) s4 += redsum[g * 4 + ow][lg * 4 + r];
        l_run[g][r] = l_run[g][r] * alpha[g][r] + s4;
        m_run[g][r] = mnew[g][r];
      }
    }
#pragma unroll
    for (int g = 0; g < 2; ++g) {
#pragma unroll
      for (int nt = 0; nt < 4; ++nt) {
#pragma unroll
        for (int r = 0; r < 4; ++r) o[g * 4 + nt][r] *= alpha[g][r];
      }
    }
#pragma unroll
    for (int kc = 0; kc < 2; ++kc) {
      bf16x8 aP0 = *(const bf16x8*)(&P_lds[l15][kc * 32 + lg * 8]);
      bf16x8 aP1 = *(const bf16x8*)(&P_lds[16 + l15][kc * 32 + lg * 8]);
#pragma unroll
      for (int nt = 0; nt < 4; ++nt) {
        int n = col0 + nt * 16 + l15;
        bf16x8 bV = *(const bf16x8*)(Vt + (size_t)n * PP + key0 + kc * 32 + lg * 8);
        o[nt] = mfma_bf16(aP0, bV, o[nt]);
        o[4 + nt] = mfma_bf16(aP1, bV, o[4 + nt]);
      }
    }
  }
  float inv[2][4];
#pragma unroll
  for (int g = 0; g < 2; ++g)
#pragma unroll
    for (int r = 0; r < 4; ++r) inv[g][r] = 1.0f / l_run[g][r];
#pragma unroll
  for (int g = 0; g < 2; ++g) {
#pragma unroll
    for (int nt = 0; nt < 4; ++nt) {
#pragma unroll
      for (int r = 0; r < 4; ++r)
        Fout[(size_t)(blockIdx.x * 32 + g * 16 + lg * 4 + r) * DD + col0 + nt * 16 + l15] =
            o[g * 4 + nt][r] * inv[g][r];
    }
  }
}

extern "C" void kernel_launch(void* const* d_in, const int* in_sizes, int n_in,
                              void* d_out, int out_size, void* d_ws, size_t ws_size,
                              hipStream_t stream) {
  const float* F   = (const float*)d_in[0];
  const float* Wq  = (const float*)d_in[1];
  const float* bq  = (const float*)d_in[2];
  const float* Wk  = (const float*)d_in[3];
  const float* bk  = (const float*)d_in[4];
  const float* Wv  = (const float*)d_in[5];
  const float* bv  = (const float*)d_in[6];
  const float* lam = (const float*)d_in[7];
  float* out = (float*)d_out;
  (void)bk;

  u16* ws  = (u16*)d_ws;
  u16* Fb  = ws;                               // [PP][DD]
  u16* G   = Fb + (size_t)PP * DD;             // [PP][DD]
  u16* Vt  = G + (size_t)PP * DD;              // [DD][PP]
  u16* WqT = Vt + (size_t)PP * DD;             // [DD][DD]
  u16* WkT = WqT + (size_t)DD * DD;
  u16* Wvb = WkT + (size_t)DD * DD;
  u16* MT  = Wvb + (size_t)DD * DD;
  float2* nv = (float2*)(MT + (size_t)DD * DD);  // [PP]
  float* kb  = (float*)(nv + PP);                // [DD]
  // decomposed path extras:
  u16* P        = (u16*)(kb + DD);               // [PP][PP] bf16, 134 MB
  float* partial = (float*)(P + (size_t)PP * PP); // [4][PP]
  float* rowsum  = partial + (size_t)4 * PP;     // [PP]
  size_t need = (size_t)((char*)(rowsum + PP) - (char*)d_ws);

  prep_wt_kernel<<<1024, 256, 0, stream>>>(Wq, Wk, Wv, WqT, WkT, Wvb);
  kb_kernel<<<16, 256, 0, stream>>>(Wk, bq, kb);
  prep_f_kernel<<<PP / 4, 256, 0, stream>>>(F, kb, Fb, nv);
  mt_kernel<<<dim3(8, 8), 256, 0, stream>>>(WkT, WqT, MT);
  gv_kernel<<<dim3(PP / 64, DD / 64, 2), 256, 0, stream>>>(Fb, MT, Wvb, bv, G, Vt);

  if (ws_size >= need) {
    float* Dist = out + (size_t)PP * DD;
    sd3_kernel<<<dim3(PP / 32, NSPLIT), 256, 0, stream>>>(G, Fb, nv, lam, Dist, P, partial);
    rowsum_kernel<<<PP / 256, 256, 0, stream>>>(partial, rowsum);
    pv2_kernel<<<dim3(PP / 64, 4), 256, 0, stream>>>(P, Vt, rowsum, out);
  } else {
    fused_kernel<<<PP / 32, 512, 0, stream>>>(G, Fb, Vt, nv, lam, out);
  }
}